// Round 1
// baseline (4774.608 us; speedup 1.0000x reference)
//
#include <hip/hip_runtime.h>
#include <hip/hip_bf16.h>

typedef __hip_bfloat16 bf16;
typedef __attribute__((ext_vector_type(8))) __bf16 bf16x8;
typedef __attribute__((ext_vector_type(4))) float f32x4;

#define N_NODES 32768
#define N_EDGES 262144
#define DIM 768
#define NGR 64
#define KIN 800   // 784 padded to multiple of 32

#define GLOBAL_AS __attribute__((address_space(1)))
#define LDS_AS __attribute__((address_space(3)))

__device__ __forceinline__ float gelu_f(float x) {
    return 0.5f * x * (1.0f + erff(x * 0.70710678118654752f));
}
__device__ __forceinline__ void atomAddF(float* p, float v) { unsafeAtomicAdd(p, v); }

// ---------------------------------------------------------------------------
// Transpose + cast fp32 [I][O] -> bf16 [O][Ipad] (zero-pads i in [I, Ipad))
// grid: (ceil(Ipad/32), O/32), block 256
__global__ __launch_bounds__(256)
void tcast_k(const float* __restrict__ in, bf16* __restrict__ out, int I, int O, int Ipad) {
    __shared__ float t[32][33];
    const int i0 = blockIdx.x * 32, o0 = blockIdx.y * 32;
    const int tx = threadIdx.x & 31, ty = threadIdx.x >> 5;  // 32 x 8
#pragma unroll
    for (int q = 0; q < 4; ++q) {
        int i = i0 + ty + q * 8, o = o0 + tx;
        t[ty + q * 8][tx] = (i < I) ? in[(size_t)i * O + o] : 0.0f;
    }
    __syncthreads();
#pragma unroll
    for (int q = 0; q < 4; ++q) {
        int o = o0 + ty + q * 8, i = i0 + tx;
        if (i < Ipad) out[(size_t)o * Ipad + i] = __float2bfloat16(t[tx][ty + q * 8]);
    }
}

// ---------------------------------------------------------------------------
// Build X = concat(type_vec, code_vec) padded to 800, cast bf16. grid N_NODES.
__global__ __launch_bounds__(256)
void concat_k(const float* __restrict__ tv, const float* __restrict__ cv, bf16* __restrict__ X) {
    const int n = blockIdx.x;
    for (int c = threadIdx.x; c < KIN; c += 256) {
        float v = 0.0f;
        if (c < 16) v = tv[(size_t)n * 16 + c];
        else if (c < 784) v = cv[(size_t)n * DIM + (c - 16)];
        X[(size_t)n * KIN + c] = __float2bfloat16(v);
    }
}

// ---------------------------------------------------------------------------
// GEMM: C[M,Nn] = A[M,K] @ BT[Nn,K]^T.  128x128 tile, BK=32, 4 waves, MFMA.
// OM==0: fp32 store; OM==1: bf16 store.
template <int OM>
__global__ __launch_bounds__(256, 2)
void gemm_bt(const bf16* __restrict__ A, const bf16* __restrict__ BT,
             void* __restrict__ OUT, int M, int Nn, int K) {
    __shared__ __align__(16) unsigned short lA[128 * 32];
    __shared__ __align__(16) unsigned short lB[128 * 32];
    const int bn = blockIdx.x * 128;
    const int bm = blockIdx.y * 128;
    const int tid = threadIdx.x;
    const int wave = tid >> 6, lane = tid & 63;
    const int wr = wave >> 1, wc = wave & 1;
    const int l15 = lane & 15, lg = lane >> 4;

    f32x4 acc[4][4] = {};

    for (int k0 = 0; k0 < K; k0 += 32) {
#pragma unroll
        for (int q = 0; q < 2; ++q) {
            int c = wave * 128 + q * 64 + lane;   // chunk id 0..511 (16B chunks)
            int row = c >> 2, k8 = c & 3;
            const bf16* ga = A + (size_t)(bm + row) * K + k0 + k8 * 8;
            const bf16* gb = BT + (size_t)(bn + row) * K + k0 + k8 * 8;
            __builtin_amdgcn_global_load_lds((const GLOBAL_AS void*)ga,
                (LDS_AS void*)&lA[(wave * 128 + q * 64) * 8], 16, 0, 0);
            __builtin_amdgcn_global_load_lds((const GLOBAL_AS void*)gb,
                (LDS_AS void*)&lB[(wave * 128 + q * 64) * 8], 16, 0, 0);
        }
        __syncthreads();
        bf16x8 af[4], bfr[4];
#pragma unroll
        for (int mi = 0; mi < 4; ++mi)
            af[mi] = *reinterpret_cast<const bf16x8*>(&lA[(wr * 64 + mi * 16 + l15) * 32 + lg * 8]);
#pragma unroll
        for (int ni = 0; ni < 4; ++ni)
            bfr[ni] = *reinterpret_cast<const bf16x8*>(&lB[(wc * 64 + ni * 16 + l15) * 32 + lg * 8]);
#pragma unroll
        for (int mi = 0; mi < 4; ++mi)
#pragma unroll
            for (int ni = 0; ni < 4; ++ni)
                acc[mi][ni] = __builtin_amdgcn_mfma_f32_16x16x32_bf16(af[mi], bfr[ni], acc[mi][ni], 0, 0, 0);
        __syncthreads();
    }

#pragma unroll
    for (int mi = 0; mi < 4; ++mi)
#pragma unroll
        for (int ni = 0; ni < 4; ++ni) {
            const int r0 = bm + wr * 64 + mi * 16 + lg * 4;
            const int c0 = bn + wc * 64 + ni * 16 + l15;
#pragma unroll
            for (int i = 0; i < 4; ++i) {
                size_t idx = (size_t)(r0 + i) * Nn + c0;
                if (OM == 0) ((float*)OUT)[idx] = acc[mi][ni][i];
                else ((bf16*)OUT)[idx] = __float2bfloat16(acc[mi][ni][i]);
            }
        }
}

// ---------------------------------------------------------------------------
// Fused bias + LayerNorm + GELU epilogue; wave per row. grid N/4, block 256.
__global__ __launch_bounds__(256)
void ln_gelu_k(const float* __restrict__ ACC, const float* __restrict__ bias,
               const float* __restrict__ g, const float* __restrict__ b,
               bf16* __restrict__ hout) {
    const int wave = threadIdx.x >> 6, lane = threadIdx.x & 63;
    const int n = blockIdx.x * 4 + wave;
    float x[12];
    float s = 0.f, ss = 0.f;
#pragma unroll
    for (int j = 0; j < 12; ++j) {
        int c = lane + j * 64;
        x[j] = ACC[(size_t)n * DIM + c] + bias[c];
        s += x[j]; ss += x[j] * x[j];
    }
#pragma unroll
    for (int m = 1; m < 64; m <<= 1) { s += __shfl_xor(s, m, 64); ss += __shfl_xor(ss, m, 64); }
    const float mean = s * (1.f / DIM);
    const float var = ss * (1.f / DIM) - mean * mean;
    const float rstd = rsqrtf(var + 1e-5f);
#pragma unroll
    for (int j = 0; j < 12; ++j) {
        int c = lane + j * 64;
        float y = (x[j] - mean) * rstd * g[c] + b[c];
        hout[(size_t)n * DIM + c] = __float2bfloat16(gelu_f(y));
    }
}

// ---------------------------------------------------------------------------
// Edge scatter: for edges with type==r: ACC[dst] += H[src]. wave handles 8 edges.
// grid 8192, block 256.
__global__ __launch_bounds__(256)
void scatter_k(const bf16* __restrict__ H, float* __restrict__ ACC,
               const int* __restrict__ src, const int* __restrict__ dst,
               const int* __restrict__ et, int r) {
    const int wv = (blockIdx.x * 256 + threadIdx.x) >> 6;
    const int lane = threadIdx.x & 63;
    const int e0 = wv * 8;
#pragma unroll
    for (int k = 0; k < 8; ++k) {
        const int e = e0 + k;
        if (et[e] != r) continue;
        const size_t s = (size_t)src[e] * DIM, d = (size_t)dst[e] * DIM;
#pragma unroll
        for (int j = 0; j < 12; ++j) {
            int c = lane + j * 64;
            atomAddF(&ACC[d + c], __bfloat162float(H[s + c]));
        }
    }
}

// ---------------------------------------------------------------------------
// gate[n] = gelu(G1[n,:] + bg1) . Wg2 + bg2 ; wave per node. grid N/4.
__global__ __launch_bounds__(256)
void gate_k(const float* __restrict__ G1, const float* __restrict__ bg1,
            const float* __restrict__ Wg2, const float* __restrict__ bg2,
            float* __restrict__ gate) {
    const int wave = threadIdx.x >> 6, lane = threadIdx.x & 63;
    const int n = blockIdx.x * 4 + wave;
    float acc = 0.f;
#pragma unroll
    for (int j = 0; j < 6; ++j) {
        int c = lane + j * 64;
        float xv = G1[(size_t)n * 384 + c] + bg1[c];
        acc += gelu_f(xv) * Wg2[c];
    }
#pragma unroll
    for (int m = 1; m < 64; m <<= 1) acc += __shfl_xor(acc, m, 64);
    if (lane == 0) gate[n] = acc + bg2[0];
}

// ---------------------------------------------------------------------------
// Per-graph max and softmax denom. block per graph (64 blocks, 256 thr).
__global__ __launch_bounds__(256)
void seg_stats_k(const float* __restrict__ gate, const int* __restrict__ ng,
                 float* __restrict__ gmax, float* __restrict__ gden) {
    __shared__ float red[256];
    const int b = blockIdx.x, t = threadIdx.x;
    float m = -1e30f;
    for (int n = t; n < N_NODES; n += 256)
        if (ng[n] == b) m = fmaxf(m, gate[n]);
    red[t] = m; __syncthreads();
    for (int s = 128; s > 0; s >>= 1) { if (t < s) red[t] = fmaxf(red[t], red[t + s]); __syncthreads(); }
    const float gm = red[0]; __syncthreads();
    float ssum = 0.f;
    for (int n = t; n < N_NODES; n += 256)
        if (ng[n] == b) ssum += expf(gate[n] - gm);
    red[t] = ssum; __syncthreads();
    for (int s = 128; s > 0; s >>= 1) { if (t < s) red[t] += red[t + s]; __syncthreads(); }
    if (t == 0) { gmax[b] = gm; gden[b] = red[0]; }
}

// ---------------------------------------------------------------------------
// Weighted pooling: grep[g] += w_n * h[n]. wave per node. grid N/4.
__global__ __launch_bounds__(256)
void pool_k(const bf16* __restrict__ h, const float* __restrict__ gate,
            const int* __restrict__ ng, const float* __restrict__ gmax,
            const float* __restrict__ gden, float* __restrict__ grep) {
    const int wave = threadIdx.x >> 6, lane = threadIdx.x & 63;
    const int n = blockIdx.x * 4 + wave;
    const int g = ng[n];
    const float wt = expf(gate[n] - gmax[g]) / gden[g];
#pragma unroll
    for (int j = 0; j < 12; ++j) {
        int c = lane + j * 64;
        atomAddF(&grep[(size_t)g * DIM + c], wt * __bfloat162float(h[(size_t)n * DIM + c]));
    }
}

// ---------------------------------------------------------------------------
// Classifier head: block per graph, 512 threads. fp32 throughout.
__global__ __launch_bounds__(512)
void cls_k(const float* __restrict__ grep, const float* __restrict__ Wc1,
           const float* __restrict__ bc1, const float* __restrict__ lng,
           const float* __restrict__ lnb, const float* __restrict__ Wc2,
           const float* __restrict__ bc2, float* __restrict__ out) {
    __shared__ float gr[DIM];
    __shared__ float red[512];
    const int b = blockIdx.x, j = threadIdx.x;
    for (int c = j; c < DIM; c += 512) gr[c] = grep[(size_t)b * DIM + c];
    __syncthreads();
    float a = bc1[j];
#pragma unroll 4
    for (int k = 0; k < DIM; ++k) a = fmaf(gr[k], Wc1[(size_t)k * 512 + j], a);
    red[j] = a; __syncthreads();
    for (int s = 256; s > 0; s >>= 1) { if (j < s) red[j] += red[j + s]; __syncthreads(); }
    const float mean = red[0] * (1.f / 512.f);
    __syncthreads();
    red[j] = (a - mean) * (a - mean); __syncthreads();
    for (int s = 256; s > 0; s >>= 1) { if (j < s) red[j] += red[j + s]; __syncthreads(); }
    const float rstd = rsqrtf(red[0] * (1.f / 512.f) + 1e-5f);
    __syncthreads();
    const float z = gelu_f((a - mean) * rstd * lng[j] + lnb[j]);
    red[j] = z * Wc2[2 * j + 0]; __syncthreads();
    for (int s = 256; s > 0; s >>= 1) { if (j < s) red[j] += red[j + s]; __syncthreads(); }
    const float l0 = red[0] + bc2[0];
    __syncthreads();
    red[j] = z * Wc2[2 * j + 1]; __syncthreads();
    for (int s = 256; s > 0; s >>= 1) { if (j < s) red[j] += red[j + s]; __syncthreads(); }
    if (j == 0) {
        const float l1 = red[0] + bc2[1];
        const float mx = fmaxf(l0, l1);
        const float lse = mx + logf(expf(l0 - mx) + expf(l1 - mx));
        out[2 * b + 0] = l0 - lse;
        out[2 * b + 1] = l1 - lse;
    }
}

// ---------------------------------------------------------------------------
extern "C" void kernel_launch(void* const* d_in, const int* in_sizes, int n_in,
                              void* d_out, int out_size, void* d_ws, size_t ws_size,
                              hipStream_t stream) {
    const float* type_vec = (const float*)d_in[0];
    const float* code_vec = (const float*)d_in[1];
    const float* W_in     = (const float*)d_in[2];
    const float* b_in     = (const float*)d_in[3];
    const float* ln_in_g  = (const float*)d_in[4];
    const float* ln_in_b  = (const float*)d_in[5];
    const float* W_rel    = (const float*)d_in[6];
    const float* W_loop   = (const float*)d_in[7];
    const float* rgcn_bias= (const float*)d_in[8];
    const float* ln_g     = (const float*)d_in[9];
    const float* ln_b     = (const float*)d_in[10];
    const float* Wg1      = (const float*)d_in[11];
    const float* bg1      = (const float*)d_in[12];
    const float* Wg2      = (const float*)d_in[13];
    const float* bg2      = (const float*)d_in[14];
    const float* Wc1      = (const float*)d_in[15];
    const float* bc1      = (const float*)d_in[16];
    const float* ln_c_g   = (const float*)d_in[17];
    const float* ln_c_b   = (const float*)d_in[18];
    const float* Wc2      = (const float*)d_in[19];
    const float* bc2      = (const float*)d_in[20];
    const int* src        = (const int*)d_in[21];
    const int* dst        = (const int*)d_in[22];
    const int* etype      = (const int*)d_in[23];
    const int* node_graph = (const int*)d_in[24];

    char* ws = (char*)d_ws;
    // workspace layout (256-aligned), total ~226 MiB
    const size_t OFF_H    = 0;                                   // bf16 [N,768]
    const size_t OFF_ACC  = 50331648;                            // f32  [N,768]
    const size_t OFF_WIN  = 150994944;                           // bf16 [768][800]
    const size_t OFF_WREL = OFF_WIN + 1228800;                   // bf16 [24][768][768]
    const size_t OFF_WLOOP= OFF_WREL + 28311552;                 // bf16 [3][768][768]
    const size_t OFF_WG1  = OFF_WLOOP + 3538944;                 // bf16 [384][768]
    const size_t OFF_X    = OFF_WG1 + 589824;                    // bf16 [N,800] (reused: H_r)
    const size_t OFF_GATE = OFF_X + (size_t)N_NODES * DIM * 2;   // f32 [N]
    const size_t OFF_GMAX = OFF_GATE + (size_t)N_NODES * 4;      // f32 [64]
    const size_t OFF_GDEN = OFF_GMAX + 256;                      // f32 [64]
    const size_t OFF_GREP = OFF_GDEN + 256;                      // f32 [64,768]

    bf16* h_bf  = (bf16*)(ws + OFF_H);
    float* ACC  = (float*)(ws + OFF_ACC);
    bf16* WinT  = (bf16*)(ws + OFF_WIN);
    bf16* WrelT = (bf16*)(ws + OFF_WREL);
    bf16* WloopT= (bf16*)(ws + OFF_WLOOP);
    bf16* Wg1T  = (bf16*)(ws + OFF_WG1);
    bf16* Xbf   = (bf16*)(ws + OFF_X);
    bf16* Hbf   = (bf16*)(ws + OFF_X);     // reuse after input proj
    float* G1   = (float*)(ws + OFF_ACC);  // reuse after layers
    float* gate = (float*)(ws + OFF_GATE);
    float* gmax = (float*)(ws + OFF_GMAX);
    float* gden = (float*)(ws + OFF_GDEN);
    float* grep = (float*)(ws + OFF_GREP);

    // --- weight prep (transpose + bf16 cast)
    tcast_k<<<dim3(25, 24), 256, 0, stream>>>(W_in, WinT, 784, DIM, KIN);
    for (int lr = 0; lr < 24; ++lr)
        tcast_k<<<dim3(24, 24), 256, 0, stream>>>(W_rel + (size_t)lr * DIM * DIM,
                                                  WrelT + (size_t)lr * DIM * DIM, DIM, DIM, DIM);
    for (int l = 0; l < 3; ++l)
        tcast_k<<<dim3(24, 24), 256, 0, stream>>>(W_loop + (size_t)l * DIM * DIM,
                                                  WloopT + (size_t)l * DIM * DIM, DIM, DIM, DIM);
    tcast_k<<<dim3(24, 12), 256, 0, stream>>>(Wg1, Wg1T, DIM, 384, DIM);

    // --- input projection
    concat_k<<<N_NODES, 256, 0, stream>>>(type_vec, code_vec, Xbf);
    gemm_bt<0><<<dim3(DIM / 128, N_NODES / 128), 256, 0, stream>>>(Xbf, WinT, ACC, N_NODES, DIM, KIN);
    ln_gelu_k<<<N_NODES / 4, 256, 0, stream>>>(ACC, b_in, ln_in_g, ln_in_b, h_bf);

    // --- RGCN layers
    for (int l = 0; l < 3; ++l) {
        gemm_bt<0><<<dim3(DIM / 128, N_NODES / 128), 256, 0, stream>>>(
            h_bf, WloopT + (size_t)l * DIM * DIM, ACC, N_NODES, DIM, DIM);
        for (int r = 0; r < 8; ++r) {
            gemm_bt<1><<<dim3(DIM / 128, N_NODES / 128), 256, 0, stream>>>(
                h_bf, WrelT + (size_t)(l * 8 + r) * DIM * DIM, Hbf, N_NODES, DIM, DIM);
            scatter_k<<<8192, 256, 0, stream>>>(Hbf, ACC, src, dst, etype, r);
        }
        ln_gelu_k<<<N_NODES / 4, 256, 0, stream>>>(ACC, rgcn_bias + l * DIM, ln_g + l * DIM,
                                                   ln_b + l * DIM, h_bf);
    }

    // --- global attention pooling
    gemm_bt<0><<<dim3(384 / 128, N_NODES / 128), 256, 0, stream>>>(h_bf, Wg1T, G1, N_NODES, 384, DIM);
    gate_k<<<N_NODES / 4, 256, 0, stream>>>(G1, bg1, Wg2, bg2, gate);
    seg_stats_k<<<NGR, 256, 0, stream>>>(gate, node_graph, gmax, gden);
    hipMemsetAsync(grep, 0, (size_t)NGR * DIM * 4, stream);
    pool_k<<<N_NODES / 4, 256, 0, stream>>>(h_bf, gate, node_graph, gmax, gden, grep);

    // --- classifier head
    cls_k<<<NGR, 512, 0, stream>>>(grep, Wc1, bc1, ln_c_g, ln_c_b, Wc2, bc2, (float*)d_out);
}

// Round 2
// 4564.375 us; speedup vs baseline: 1.0461x; 1.0461x over previous
//
#include <hip/hip_runtime.h>
#include <hip/hip_bf16.h>

typedef __hip_bfloat16 bf16;
typedef __attribute__((ext_vector_type(8))) __bf16 bf16x8;
typedef __attribute__((ext_vector_type(4))) float f32x4;

#define N_NODES 32768
#define N_EDGES 262144
#define DIM 768
#define NGR 64
#define KIN 800     // 784 padded to 32
#define KAGG 6144   // 8*768
#define KSTACK 6912 // 8*768 + 768 (self-loop)

#define GLOBAL_AS __attribute__((address_space(1)))
#define LDS_AS __attribute__((address_space(3)))

__device__ __forceinline__ float gelu_f(float x) {
    return 0.5f * x * (1.0f + erff(x * 0.70710678118654752f));
}
__device__ __forceinline__ float bfu(unsigned short v) {
    union { unsigned u; float f; } x; x.u = (unsigned)v << 16; return x.f;
}
__device__ __forceinline__ unsigned short fbf(float f) {
    bf16 t = __float2bfloat16(f); return *(unsigned short*)&t;
}
__device__ __forceinline__ void atomAddF(float* p, float v) { unsafeAtomicAdd(p, v); }

// ---------------------------------------------------------------------------
// Transpose + cast fp32 [I][O] -> bf16 [O][ostride] (zero-pads i in [I,Ipad))
__global__ __launch_bounds__(256)
void tcast_k(const float* __restrict__ in, bf16* __restrict__ out, int I, int O,
             int Ipad, int ostride) {
    __shared__ float t[32][33];
    const int i0 = blockIdx.x * 32, o0 = blockIdx.y * 32;
    const int tx = threadIdx.x & 31, ty = threadIdx.x >> 5;
#pragma unroll
    for (int q = 0; q < 4; ++q) {
        int i = i0 + ty + q * 8, o = o0 + tx;
        t[ty + q * 8][tx] = (i < I) ? in[(size_t)i * O + o] : 0.0f;
    }
    __syncthreads();
#pragma unroll
    for (int q = 0; q < 4; ++q) {
        int o = o0 + ty + q * 8, i = i0 + tx;
        if (i < Ipad) out[(size_t)o * ostride + i] = __float2bfloat16(t[tx][ty + q * 8]);
    }
}

// ---------------------------------------------------------------------------
// All RGCN weights -> WstackT[l][768 out][6912 K]. grid (24,24,27).
__global__ __launch_bounds__(256)
void wprep_k(const float* __restrict__ W_rel, const float* __restrict__ W_loop,
             bf16* __restrict__ Wst) {
    __shared__ float t[32][33];
    const int z = blockIdx.z, l = z / 9, q = z % 9;
    const float* in = (q < 8) ? W_rel + ((size_t)(l * 8 + q)) * DIM * DIM
                              : W_loop + (size_t)l * DIM * DIM;
    bf16* out = Wst + (size_t)l * DIM * KSTACK + (q < 8 ? q * DIM : KAGG);
    const int i0 = blockIdx.x * 32, o0 = blockIdx.y * 32;
    const int tx = threadIdx.x & 31, ty = threadIdx.x >> 5;
#pragma unroll
    for (int qq = 0; qq < 4; ++qq)
        t[ty + qq * 8][tx] = in[(size_t)(i0 + ty + qq * 8) * DIM + o0 + tx];
    __syncthreads();
#pragma unroll
    for (int qq = 0; qq < 4; ++qq)
        out[(size_t)(o0 + ty + qq * 8) * KSTACK + i0 + tx] =
            __float2bfloat16(t[tx][ty + qq * 8]);
}

// ---------------------------------------------------------------------------
__global__ __launch_bounds__(256)
void concat_k(const float* __restrict__ tv, const float* __restrict__ cv, bf16* __restrict__ X) {
    const int n = blockIdx.x;
    for (int c = threadIdx.x; c < KIN; c += 256) {
        float v = 0.0f;
        if (c < 16) v = tv[(size_t)n * 16 + c];
        else if (c < 784) v = cv[(size_t)n * DIM + (c - 16)];
        X[(size_t)n * KIN + c] = __float2bfloat16(v);
    }
}

// ---------------------------------------------------------------------------
// CSR build
__global__ __launch_bounds__(256)
void hist_k(const int* __restrict__ dst, int* __restrict__ deg) {
    int e = blockIdx.x * 256 + threadIdx.x;
    if (e < N_EDGES) atomicAdd(&deg[dst[e]], 1);
}

__global__ __launch_bounds__(1024)
void scan_k(const int* __restrict__ deg, int* __restrict__ row_ptr, int* __restrict__ cursor) {
    __shared__ int part[1024];
    const int t = threadIdx.x;
    int loc[32]; int s = 0;
#pragma unroll
    for (int i = 0; i < 32; ++i) { loc[i] = s; s += deg[t * 32 + i]; }
    part[t] = s; __syncthreads();
    for (int st = 1; st < 1024; st <<= 1) {
        int v = (t >= st) ? part[t - st] : 0;
        __syncthreads();
        part[t] += v;
        __syncthreads();
    }
    const int base = part[t] - s;  // exclusive prefix
#pragma unroll
    for (int i = 0; i < 32; ++i) { int v = base + loc[i]; row_ptr[t * 32 + i] = v; cursor[t * 32 + i] = v; }
    if (t == 1023) row_ptr[N_NODES] = part[1023];
}

__global__ __launch_bounds__(256)
void place_k(const int* __restrict__ src, const int* __restrict__ dst,
             const int* __restrict__ et, int* __restrict__ cursor, int* __restrict__ eidx) {
    int e = blockIdx.x * 256 + threadIdx.x;
    if (e >= N_EDGES) return;
    int d = dst[e];
    int pos = atomicAdd(&cursor[d], 1);
    eidx[pos] = (src[e] & 0xffff) | (et[e] << 16);
}

// ---------------------------------------------------------------------------
// Gather-aggregate: AGG[n][r*768+c] = sum over in-edges of type r of h[src][c].
// wave per node, grid N/4, block 256.
__global__ __launch_bounds__(256)
void gather_k(const bf16* __restrict__ h, const int* __restrict__ row_ptr,
              const int* __restrict__ eidx, bf16* __restrict__ AGG) {
    const int wave = threadIdx.x >> 6, lane = threadIdx.x & 63;
    const int n = blockIdx.x * 4 + wave;
    const int start = row_ptr[n], end = row_ptr[n + 1];
    const int c0 = 2 * lane;
    unsigned short* outrow = (unsigned short*)&AGG[(size_t)n * KAGG];
#pragma unroll 1
    for (int r = 0; r < 8; ++r) {
        float2 f[6];
#pragma unroll
        for (int j = 0; j < 6; ++j) { f[j].x = 0.f; f[j].y = 0.f; }
        for (int e = start; e < end; ++e) {
            int pk = eidx[e];
            if ((pk >> 16) != r) continue;
            const unsigned short* hs = (const unsigned short*)&h[(size_t)(pk & 0xffff) * DIM];
#pragma unroll
            for (int j = 0; j < 6; ++j) {
                ushort2 u = *(const ushort2*)&hs[c0 + j * 128];
                f[j].x += bfu(u.x); f[j].y += bfu(u.y);
            }
        }
#pragma unroll
        for (int j = 0; j < 6; ++j) {
            ushort2 o; o.x = fbf(f[j].x); o.y = fbf(f[j].y);
            *(ushort2*)&outrow[r * DIM + c0 + j * 128] = o;
        }
    }
}

// ---------------------------------------------------------------------------
// GEMM: C[M,Nn] = A[M,Ktot] @ BT[Nn,Ktot]^T, where A is split: rows come from
// A1 (cols [0,K1), stride S1) then A2 (cols [K1,Ktot), stride S2).
// 128x128 tile, BK=32, 4 waves. OM==0: fp32 store; OM==1: bf16 store.
template <int OM>
__global__ __launch_bounds__(256, 2)
void gemm_bt(const bf16* __restrict__ A1, int S1, int K1,
             const bf16* __restrict__ A2, int S2,
             const bf16* __restrict__ BT, int ldb,
             void* __restrict__ OUT, int Nn, int Ktot) {
    __shared__ __align__(16) unsigned short lA[128 * 32];
    __shared__ __align__(16) unsigned short lB[128 * 32];
    const int bn = blockIdx.x * 128;
    const int bm = blockIdx.y * 128;
    const int tid = threadIdx.x;
    const int wave = tid >> 6, lane = tid & 63;
    const int wr = wave >> 1, wc = wave & 1;
    const int l15 = lane & 15, lg = lane >> 4;

    f32x4 acc[4][4] = {};

    for (int k0 = 0; k0 < Ktot; k0 += 32) {
        const bf16* Ab; int koff, stA;
        if (k0 < K1) { Ab = A1; koff = k0; stA = S1; }
        else         { Ab = A2; koff = k0 - K1; stA = S2; }
#pragma unroll
        for (int q = 0; q < 2; ++q) {
            int c = wave * 128 + q * 64 + lane;   // chunk id 0..511 (16B chunks)
            int row = c >> 2, k8 = c & 3;
            const bf16* ga = Ab + (size_t)(bm + row) * stA + koff + k8 * 8;
            const bf16* gb = BT + (size_t)(bn + row) * ldb + k0 + k8 * 8;
            __builtin_amdgcn_global_load_lds((const GLOBAL_AS void*)ga,
                (LDS_AS void*)&lA[(wave * 128 + q * 64) * 8], 16, 0, 0);
            __builtin_amdgcn_global_load_lds((const GLOBAL_AS void*)gb,
                (LDS_AS void*)&lB[(wave * 128 + q * 64) * 8], 16, 0, 0);
        }
        __syncthreads();
        bf16x8 af[4], bfr[4];
#pragma unroll
        for (int mi = 0; mi < 4; ++mi)
            af[mi] = *reinterpret_cast<const bf16x8*>(&lA[(wr * 64 + mi * 16 + l15) * 32 + lg * 8]);
#pragma unroll
        for (int ni = 0; ni < 4; ++ni)
            bfr[ni] = *reinterpret_cast<const bf16x8*>(&lB[(wc * 64 + ni * 16 + l15) * 32 + lg * 8]);
#pragma unroll
        for (int mi = 0; mi < 4; ++mi)
#pragma unroll
            for (int ni = 0; ni < 4; ++ni)
                acc[mi][ni] = __builtin_amdgcn_mfma_f32_16x16x32_bf16(af[mi], bfr[ni], acc[mi][ni], 0, 0, 0);
        __syncthreads();
    }

#pragma unroll
    for (int mi = 0; mi < 4; ++mi)
#pragma unroll
        for (int ni = 0; ni < 4; ++ni) {
            const int r0 = bm + wr * 64 + mi * 16 + lg * 4;
            const int c0 = bn + wc * 64 + ni * 16 + l15;
#pragma unroll
            for (int i = 0; i < 4; ++i) {
                size_t idx = (size_t)(r0 + i) * Nn + c0;
                if (OM == 0) ((float*)OUT)[idx] = acc[mi][ni][i];
                else ((bf16*)OUT)[idx] = __float2bfloat16(acc[mi][ni][i]);
            }
        }
}

// ---------------------------------------------------------------------------
// Fused bias + LayerNorm + GELU; wave per row. grid N/4, block 256.
__global__ __launch_bounds__(256)
void ln_gelu_k(const float* __restrict__ ACC, const float* __restrict__ bias,
               const float* __restrict__ g, const float* __restrict__ b,
               bf16* __restrict__ hout) {
    const int wave = threadIdx.x >> 6, lane = threadIdx.x & 63;
    const int n = blockIdx.x * 4 + wave;
    float x[12];
    float s = 0.f, ss = 0.f;
#pragma unroll
    for (int j = 0; j < 12; ++j) {
        int c = lane + j * 64;
        x[j] = ACC[(size_t)n * DIM + c] + bias[c];
        s += x[j]; ss += x[j] * x[j];
    }
#pragma unroll
    for (int m = 1; m < 64; m <<= 1) { s += __shfl_xor(s, m, 64); ss += __shfl_xor(ss, m, 64); }
    const float mean = s * (1.f / DIM);
    const float var = ss * (1.f / DIM) - mean * mean;
    const float rstd = rsqrtf(var + 1e-5f);
#pragma unroll
    for (int j = 0; j < 12; ++j) {
        int c = lane + j * 64;
        float y = (x[j] - mean) * rstd * g[c] + b[c];
        hout[(size_t)n * DIM + c] = __float2bfloat16(gelu_f(y));
    }
}

// ---------------------------------------------------------------------------
// Fallback scatter (only used if workspace too small for the gather path)
__global__ __launch_bounds__(256)
void scatter_k(const bf16* __restrict__ H, float* __restrict__ ACC,
               const int* __restrict__ src, const int* __restrict__ dst,
               const int* __restrict__ et, int r) {
    const int wv = (blockIdx.x * 256 + threadIdx.x) >> 6;
    const int lane = threadIdx.x & 63;
    const int e0 = wv * 8;
#pragma unroll
    for (int k = 0; k < 8; ++k) {
        const int e = e0 + k;
        if (et[e] != r) continue;
        const size_t s = (size_t)src[e] * DIM, d = (size_t)dst[e] * DIM;
#pragma unroll
        for (int j = 0; j < 12; ++j) {
            int c = lane + j * 64;
            atomAddF(&ACC[d + c], __bfloat162float(H[s + c]));
        }
    }
}

// ---------------------------------------------------------------------------
__global__ __launch_bounds__(256)
void gate_k(const float* __restrict__ G1, const float* __restrict__ bg1,
            const float* __restrict__ Wg2, const float* __restrict__ bg2,
            float* __restrict__ gate) {
    const int wave = threadIdx.x >> 6, lane = threadIdx.x & 63;
    const int n = blockIdx.x * 4 + wave;
    float acc = 0.f;
#pragma unroll
    for (int j = 0; j < 6; ++j) {
        int c = lane + j * 64;
        float xv = G1[(size_t)n * 384 + c] + bg1[c];
        acc += gelu_f(xv) * Wg2[c];
    }
#pragma unroll
    for (int m = 1; m < 64; m <<= 1) acc += __shfl_xor(acc, m, 64);
    if (lane == 0) gate[n] = acc + bg2[0];
}

// ---------------------------------------------------------------------------
__device__ __forceinline__ int lower_bound_ng(const int* ng, int key) {
    int lo = 0, hi = N_NODES;
    while (lo < hi) { int mid = (lo + hi) >> 1; if (ng[mid] < key) lo = mid + 1; else hi = mid; }
    return lo;
}

// Per-graph max + softmax denom; node_graph is sorted -> binary search range.
__global__ __launch_bounds__(256)
void seg_stats_k(const float* __restrict__ gate, const int* __restrict__ ng,
                 float* __restrict__ gmax, float* __restrict__ gden) {
    __shared__ float red[256];
    const int b = blockIdx.x, t = threadIdx.x;
    const int start = lower_bound_ng(ng, b), end = lower_bound_ng(ng, b + 1);
    float m = -1e30f;
    for (int n = start + t; n < end; n += 256) m = fmaxf(m, gate[n]);
    red[t] = m; __syncthreads();
    for (int s = 128; s > 0; s >>= 1) { if (t < s) red[t] = fmaxf(red[t], red[t + s]); __syncthreads(); }
    const float gm = red[0]; __syncthreads();
    float ssum = 0.f;
    for (int n = start + t; n < end; n += 256) ssum += expf(gate[n] - gm);
    red[t] = ssum; __syncthreads();
    for (int s = 128; s > 0; s >>= 1) { if (t < s) red[t] += red[t + s]; __syncthreads(); }
    if (t == 0) { gmax[b] = gm; gden[b] = fmaxf(red[0], 1e-30f); }
}

// Weighted pooling, atomic-free: block per graph, thread per dim.
__global__ __launch_bounds__(768)
void pool_k(const bf16* __restrict__ h, const float* __restrict__ gate,
            const int* __restrict__ ng, const float* __restrict__ gmax,
            const float* __restrict__ gden, float* __restrict__ grep) {
    const int b = blockIdx.x, c = threadIdx.x;
    const int start = lower_bound_ng(ng, b), end = lower_bound_ng(ng, b + 1);
    const float gm = gmax[b], inv = 1.0f / gden[b];
    const unsigned short* hv = (const unsigned short*)h;
    float a0 = 0.f, a1 = 0.f;
    int n = start;
    for (; n + 1 < end; n += 2) {
        float w0 = expf(gate[n] - gm) * inv;
        float w1 = expf(gate[n + 1] - gm) * inv;
        a0 += w0 * bfu(hv[(size_t)n * DIM + c]);
        a1 += w1 * bfu(hv[(size_t)(n + 1) * DIM + c]);
    }
    if (n < end) a0 += expf(gate[n] - gm) * inv * bfu(hv[(size_t)n * DIM + c]);
    grep[(size_t)b * DIM + c] = a0 + a1;
}

// ---------------------------------------------------------------------------
// Classifier head: block per graph, 512 threads, fp32.
__global__ __launch_bounds__(512)
void cls_k(const float* __restrict__ grep, const float* __restrict__ Wc1,
           const float* __restrict__ bc1, const float* __restrict__ lng,
           const float* __restrict__ lnb, const float* __restrict__ Wc2,
           const float* __restrict__ bc2, float* __restrict__ out) {
    __shared__ float gr[DIM];
    __shared__ float red[512];
    const int b = blockIdx.x, j = threadIdx.x;
    for (int c = j; c < DIM; c += 512) gr[c] = grep[(size_t)b * DIM + c];
    __syncthreads();
    float a = bc1[j];
#pragma unroll 4
    for (int k = 0; k < DIM; ++k) a = fmaf(gr[k], Wc1[(size_t)k * 512 + j], a);
    red[j] = a; __syncthreads();
    for (int s = 256; s > 0; s >>= 1) { if (j < s) red[j] += red[j + s]; __syncthreads(); }
    const float mean = red[0] * (1.f / 512.f);
    __syncthreads();
    red[j] = (a - mean) * (a - mean); __syncthreads();
    for (int s = 256; s > 0; s >>= 1) { if (j < s) red[j] += red[j + s]; __syncthreads(); }
    const float rstd = rsqrtf(red[0] * (1.f / 512.f) + 1e-5f);
    __syncthreads();
    const float z = gelu_f((a - mean) * rstd * lng[j] + lnb[j]);
    red[j] = z * Wc2[2 * j + 0]; __syncthreads();
    for (int s = 256; s > 0; s >>= 1) { if (j < s) red[j] += red[j + s]; __syncthreads(); }
    const float l0 = red[0] + bc2[0];
    __syncthreads();
    red[j] = z * Wc2[2 * j + 1]; __syncthreads();
    for (int s = 256; s > 0; s >>= 1) { if (j < s) red[j] += red[j + s]; __syncthreads(); }
    if (j == 0) {
        const float l1 = red[0] + bc2[1];
        const float mx = fmaxf(l0, l1);
        const float lse = mx + logf(expf(l0 - mx) + expf(l1 - mx));
        out[2 * b + 0] = l0 - lse;
        out[2 * b + 1] = l1 - lse;
    }
}

// ---------------------------------------------------------------------------
extern "C" void kernel_launch(void* const* d_in, const int* in_sizes, int n_in,
                              void* d_out, int out_size, void* d_ws, size_t ws_size,
                              hipStream_t stream) {
    const float* type_vec = (const float*)d_in[0];
    const float* code_vec = (const float*)d_in[1];
    const float* W_in     = (const float*)d_in[2];
    const float* b_in     = (const float*)d_in[3];
    const float* ln_in_g  = (const float*)d_in[4];
    const float* ln_in_b  = (const float*)d_in[5];
    const float* W_rel    = (const float*)d_in[6];
    const float* W_loop   = (const float*)d_in[7];
    const float* rgcn_bias= (const float*)d_in[8];
    const float* ln_g     = (const float*)d_in[9];
    const float* ln_b     = (const float*)d_in[10];
    const float* Wg1      = (const float*)d_in[11];
    const float* bg1      = (const float*)d_in[12];
    const float* Wg2      = (const float*)d_in[13];
    const float* bg2      = (const float*)d_in[14];
    const float* Wc1      = (const float*)d_in[15];
    const float* bc1      = (const float*)d_in[16];
    const float* ln_c_g   = (const float*)d_in[17];
    const float* ln_c_b   = (const float*)d_in[18];
    const float* Wc2      = (const float*)d_in[19];
    const float* bc2      = (const float*)d_in[20];
    const int* src        = (const int*)d_in[21];
    const int* dst        = (const int*)d_in[22];
    const int* etype      = (const int*)d_in[23];
    const int* node_graph = (const int*)d_in[24];

    char* ws = (char*)d_ws;

    // ---- big-path layout (~590 MB)
    const size_t OFF_H    = 0;                       // bf16 [N][768]
    const size_t OFF_ACC  = 50331648;                // f32  [N][768]
    const size_t OFF_AGG  = 150994944;               // bf16 [N][6144]  (X overlaps here)
    const size_t OFF_WIN  = 553648128;               // bf16 [768][800]
    const size_t OFF_WST  = 554876928;               // bf16 [3][768][6912]
    const size_t OFF_WG1  = 586727424;               // bf16 [384][768]
    const size_t OFF_RP   = 587317248;               // int  [32769]
    const size_t OFF_CUR  = 587448576;               // int  [32768]
    const size_t OFF_DEG  = 587579904;               // int  [32768]
    const size_t OFF_EIX  = 587711232;               // int  [E]
    const size_t OFF_GATE = 588759808;               // f32  [N]
    const size_t OFF_GMAX = 588890880;               // f32  [64]
    const size_t OFF_GDEN = 588891136;               // f32  [64]
    const size_t OFF_GREP = 588891392;               // f32  [64][768]
    const size_t NEED_BIG = 589088768;

    const bool big = ws_size >= NEED_BIG;

    // ---- small-path (round-1 style) layout (~238 MB)
    const size_t S_OFF_X   = 150994944;  // bf16 [N][800], reused as Hbf [N][768]
    const size_t S_OFF_WIN = 203423744;
    const size_t S_OFF_WST = 204652544;
    const size_t S_OFF_WG1 = 236503040;
    const size_t S_OFF_GATE= 237092864;
    const size_t S_OFF_GMAX= 237223936;
    const size_t S_OFF_GDEN= 237224192;
    const size_t S_OFF_GREP= 237224448;

    bf16* h_bf  = (bf16*)(ws + OFF_H);
    float* ACC  = (float*)(ws + OFF_ACC);
    bf16* WinT  = (bf16*)(ws + (big ? OFF_WIN : S_OFF_WIN));
    bf16* Wst   = (bf16*)(ws + (big ? OFF_WST : S_OFF_WST));
    bf16* Wg1T  = (bf16*)(ws + (big ? OFF_WG1 : S_OFF_WG1));
    bf16* Xbf   = (bf16*)(ws + (big ? OFF_AGG : S_OFF_X));
    bf16* AGG   = (bf16*)(ws + OFF_AGG);
    bf16* Hbf   = (bf16*)(ws + S_OFF_X);
    int* row_ptr= (int*)(ws + OFF_RP);
    int* cursor = (int*)(ws + OFF_CUR);
    int* deg    = (int*)(ws + OFF_DEG);
    int* eidx   = (int*)(ws + OFF_EIX);
    float* G1   = (float*)(ws + OFF_ACC);
    float* gate = (float*)(ws + (big ? OFF_GATE : S_OFF_GATE));
    float* gmax = (float*)(ws + (big ? OFF_GMAX : S_OFF_GMAX));
    float* gden = (float*)(ws + (big ? OFF_GDEN : S_OFF_GDEN));
    float* grep = (float*)(ws + (big ? OFF_GREP : S_OFF_GREP));

    // --- weight prep
    tcast_k<<<dim3(25, 24), 256, 0, stream>>>(W_in, WinT, 784, DIM, KIN, KIN);
    wprep_k<<<dim3(24, 24, 27), 256, 0, stream>>>(W_rel, W_loop, Wst);
    tcast_k<<<dim3(24, 12), 256, 0, stream>>>(Wg1, Wg1T, DIM, 384, DIM, DIM);

    // --- CSR build (big path only)
    if (big) {
        hipMemsetAsync(deg, 0, (size_t)N_NODES * 4, stream);
        hist_k<<<N_EDGES / 256, 256, 0, stream>>>(dst, deg);
        scan_k<<<1, 1024, 0, stream>>>(deg, row_ptr, cursor);
        place_k<<<N_EDGES / 256, 256, 0, stream>>>(src, dst, etype, cursor, eidx);
    }

    // --- input projection  (X lives at AGG start; consumed before AGG written)
    concat_k<<<N_NODES, 256, 0, stream>>>(type_vec, code_vec, Xbf);
    gemm_bt<0><<<dim3(DIM / 128, N_NODES / 128), 256, 0, stream>>>(
        Xbf, KIN, KIN, Xbf, KIN, WinT, KIN, ACC, DIM, KIN);
    ln_gelu_k<<<N_NODES / 4, 256, 0, stream>>>(ACC, b_in, ln_in_g, ln_in_b, h_bf);

    // --- RGCN layers
    for (int l = 0; l < 3; ++l) {
        bf16* Wl = Wst + (size_t)l * DIM * KSTACK;
        if (big) {
            gather_k<<<N_NODES / 4, 256, 0, stream>>>(h_bf, row_ptr, eidx, AGG);
            gemm_bt<0><<<dim3(DIM / 128, N_NODES / 128), 256, 0, stream>>>(
                AGG, KAGG, KAGG, h_bf, DIM, Wl, KSTACK, ACC, DIM, KSTACK);
        } else {
            gemm_bt<0><<<dim3(DIM / 128, N_NODES / 128), 256, 0, stream>>>(
                h_bf, DIM, DIM, h_bf, DIM, Wl + KAGG, KSTACK, ACC, DIM, DIM);
            for (int r = 0; r < 8; ++r) {
                gemm_bt<1><<<dim3(DIM / 128, N_NODES / 128), 256, 0, stream>>>(
                    h_bf, DIM, DIM, h_bf, DIM, Wl + r * DIM, KSTACK, Hbf, DIM, DIM);
                scatter_k<<<8192, 256, 0, stream>>>(Hbf, ACC, src, dst, etype, r);
            }
        }
        ln_gelu_k<<<N_NODES / 4, 256, 0, stream>>>(ACC, rgcn_bias + l * DIM, ln_g + l * DIM,
                                                   ln_b + l * DIM, h_bf);
    }

    // --- global attention pooling
    gemm_bt<0><<<dim3(384 / 128, N_NODES / 128), 256, 0, stream>>>(
        h_bf, DIM, DIM, h_bf, DIM, Wg1T, DIM, G1, 384, DIM);
    gate_k<<<N_NODES / 4, 256, 0, stream>>>(G1, bg1, Wg2, bg2, gate);
    seg_stats_k<<<NGR, 256, 0, stream>>>(gate, node_graph, gmax, gden);
    pool_k<<<NGR, 768, 0, stream>>>(h_bf, gate, node_graph, gmax, gden, grep);

    // --- classifier head
    cls_k<<<NGR, 512, 0, stream>>>(grep, Wc1, bc1, ln_c_g, ln_c_b, Wc2, bc2, (float*)d_out);
}

// Round 3
// 2750.591 us; speedup vs baseline: 1.7358x; 1.6594x over previous
//
#include <hip/hip_runtime.h>
#include <hip/hip_bf16.h>

typedef __hip_bfloat16 bf16;
typedef __attribute__((ext_vector_type(8))) __bf16 bf16x8;
typedef __attribute__((ext_vector_type(4))) float f32x4;

#define N_NODES 32768
#define N_EDGES 262144
#define DIM 768
#define NGR 64
#define KIN 800     // 784 padded to 32
#define KSTACK 6912 // self(768) + 8*768

#define GLOBAL_AS __attribute__((address_space(1)))
#define LDS_AS __attribute__((address_space(3)))

__device__ __forceinline__ float gelu_f(float x) {
    return 0.5f * x * (1.0f + erff(x * 0.70710678118654752f));
}
__device__ __forceinline__ float bfu(unsigned short v) {
    union { unsigned u; float f; } x; x.u = (unsigned)v << 16; return x.f;
}
__device__ __forceinline__ unsigned short fbf(float f) {
    bf16 t = __float2bfloat16(f); return *(unsigned short*)&t;
}

// ---------------------------------------------------------------------------
// Transpose + cast fp32 [I][O] -> bf16 [O][ostride], zero-pad i in [I,Ipad)
__global__ __launch_bounds__(256)
void tcast_k(const float* __restrict__ in, bf16* __restrict__ out, int I, int O,
             int Ipad, int ostride) {
    __shared__ float t[32][33];
    const int i0 = blockIdx.x * 32, o0 = blockIdx.y * 32;
    const int tx = threadIdx.x & 31, ty = threadIdx.x >> 5;
#pragma unroll
    for (int q = 0; q < 4; ++q) {
        int i = i0 + ty + q * 8, o = o0 + tx;
        t[ty + q * 8][tx] = (i < I) ? in[(size_t)i * O + o] : 0.0f;
    }
    __syncthreads();
#pragma unroll
    for (int q = 0; q < 4; ++q) {
        int o = o0 + ty + q * 8, i = i0 + tx;
        if (i < Ipad) out[(size_t)o * ostride + i] = __float2bfloat16(t[tx][ty + q * 8]);
    }
}

// ---------------------------------------------------------------------------
// RGCN weights -> Wst[l][768 out][6912 K], K order: [self | r0..r7]. grid(24,24,27)
__global__ __launch_bounds__(256)
void wprep_k(const float* __restrict__ W_rel, const float* __restrict__ W_loop,
             bf16* __restrict__ Wst) {
    __shared__ float t[32][33];
    const int z = blockIdx.z, l = z / 9, q = z % 9;
    const float* in = (q < 8) ? W_rel + ((size_t)(l * 8 + q)) * DIM * DIM
                              : W_loop + (size_t)l * DIM * DIM;
    bf16* out = Wst + (size_t)l * DIM * KSTACK + (q < 8 ? (q + 1) * DIM : 0);
    const int i0 = blockIdx.x * 32, o0 = blockIdx.y * 32;
    const int tx = threadIdx.x & 31, ty = threadIdx.x >> 5;
#pragma unroll
    for (int qq = 0; qq < 4; ++qq)
        t[ty + qq * 8][tx] = in[(size_t)(i0 + ty + qq * 8) * DIM + o0 + tx];
    __syncthreads();
#pragma unroll
    for (int qq = 0; qq < 4; ++qq)
        out[(size_t)(o0 + ty + qq * 8) * KSTACK + i0 + tx] =
            __float2bfloat16(t[tx][ty + qq * 8]);
}

// ---------------------------------------------------------------------------
__global__ __launch_bounds__(256)
void concat_k(const float* __restrict__ tv, const float* __restrict__ cv, bf16* __restrict__ X) {
    const int n = blockIdx.x;
    for (int c = threadIdx.x; c < KIN; c += 256) {
        float v = 0.0f;
        if (c < 16) v = tv[(size_t)n * 16 + c];
        else if (c < 784) v = cv[(size_t)n * DIM + (c - 16)];
        X[(size_t)n * KIN + c] = __float2bfloat16(v);
    }
}

// ---------------------------------------------------------------------------
// CSR build
__global__ __launch_bounds__(256)
void hist_k(const int* __restrict__ dst, int* __restrict__ deg) {
    int e = blockIdx.x * 256 + threadIdx.x;
    if (e < N_EDGES) atomicAdd(&deg[dst[e]], 1);
}

__global__ __launch_bounds__(1024)
void scan_k(const int* __restrict__ deg, int* __restrict__ row_ptr, int* __restrict__ cursor) {
    __shared__ int part[1024];
    const int t = threadIdx.x;
    int loc[32]; int s = 0;
#pragma unroll
    for (int i = 0; i < 32; ++i) { loc[i] = s; s += deg[t * 32 + i]; }
    part[t] = s; __syncthreads();
    for (int st = 1; st < 1024; st <<= 1) {
        int v = (t >= st) ? part[t - st] : 0;
        __syncthreads();
        part[t] += v;
        __syncthreads();
    }
    const int base = part[t] - s;
#pragma unroll
    for (int i = 0; i < 32; ++i) { int v = base + loc[i]; row_ptr[t * 32 + i] = v; cursor[t * 32 + i] = v; }
    if (t == 1023) row_ptr[N_NODES] = part[1023];
}

__global__ __launch_bounds__(256)
void place_k(const int* __restrict__ src, const int* __restrict__ dst,
             const int* __restrict__ et, int* __restrict__ cursor, int* __restrict__ eidx) {
    int e = blockIdx.x * 256 + threadIdx.x;
    if (e >= N_EDGES) return;
    int d = dst[e];
    int pos = atomicAdd(&cursor[d], 1);
    eidx[pos] = (src[e] & 0xffff) | (et[e] << 16);
}

// ---------------------------------------------------------------------------
// Gather-aggregate for NC relations [rbase, rbase+NC):
// AGG[n][sel*768+c] = sum over in-edges of type rbase+sel of h[src][c].
// wave per node, grid N/4, block 256. No atomics.
template <int NC>
__global__ __launch_bounds__(256)
void gather_k(const bf16* __restrict__ h, const int* __restrict__ row_ptr,
              const int* __restrict__ eidx, bf16* __restrict__ AGG, int rbase) {
    const int wave = threadIdx.x >> 6, lane = threadIdx.x & 63;
    const int n = blockIdx.x * 4 + wave;
    const int start = row_ptr[n], end = row_ptr[n + 1];
    const int c0 = 2 * lane;
    float2 f0[6] = {}, f1[6] = {}, f2[6] = {}, f3[6] = {};
#define ACCJ(F) _Pragma("unroll") for (int j = 0; j < 6; ++j) { F[j].x += bfu(u[j].x); F[j].y += bfu(u[j].y); }
    for (int e = start; e < end; ++e) {
        const int pk = eidx[e];
        const int sel = (pk >> 16) - rbase;
        if (sel < 0 || sel >= NC) continue;
        const unsigned short* hs = (const unsigned short*)&h[(size_t)(pk & 0xffff) * DIM];
        ushort2 u[6];
#pragma unroll
        for (int j = 0; j < 6; ++j) u[j] = *(const ushort2*)&hs[c0 + j * 128];
        if (sel == 0) { ACCJ(f0) }
        else if (NC > 1 && sel == 1) { ACCJ(f1) }
        else if (NC > 2 && sel == 2) { ACCJ(f2) }
        else if (NC > 3 && sel == 3) { ACCJ(f3) }
    }
#undef ACCJ
    unsigned short* outrow = (unsigned short*)&AGG[(size_t)n * (NC * DIM)];
#define STJ(F, S) _Pragma("unroll") for (int j = 0; j < 6; ++j) { ushort2 o; o.x = fbf(F[j].x); o.y = fbf(F[j].y); *(ushort2*)&outrow[(S) * DIM + c0 + j * 128] = o; }
    STJ(f0, 0)
    if (NC > 1) { STJ(f1, 1) }
    if (NC > 2) { STJ(f2, 2) }
    if (NC > 3) { STJ(f3, 3) }
#undef STJ
}

// ---------------------------------------------------------------------------
// GEMM: C[M,Nn](f32) (+)= A[M,Ktot] @ BT[Nn,Ktot]^T. A split: rows from A1
// (cols [0,K1), stride S1) then A2 (cols [K1,Ktot), stride S2).
// 128x128 tile, BK=32, 4 waves. ACCUM: read-modify-write C.
template <int ACCUM>
__global__ __launch_bounds__(256, 2)
void gemm_bt(const bf16* __restrict__ A1, int S1, int K1,
             const bf16* __restrict__ A2, int S2,
             const bf16* __restrict__ BT, int ldb,
             float* __restrict__ OUT, int Nn, int Ktot) {
    __shared__ __align__(16) unsigned short lA[128 * 32];
    __shared__ __align__(16) unsigned short lB[128 * 32];
    const int bn = blockIdx.x * 128;
    const int bm = blockIdx.y * 128;
    const int tid = threadIdx.x;
    const int wave = tid >> 6, lane = tid & 63;
    const int wr = wave >> 1, wc = wave & 1;
    const int l15 = lane & 15, lg = lane >> 4;

    f32x4 acc[4][4] = {};

    for (int k0 = 0; k0 < Ktot; k0 += 32) {
        const bf16* Ab; int koff, stA;
        if (k0 < K1) { Ab = A1; koff = k0; stA = S1; }
        else         { Ab = A2; koff = k0 - K1; stA = S2; }
#pragma unroll
        for (int q = 0; q < 2; ++q) {
            int c = wave * 128 + q * 64 + lane;
            int row = c >> 2, k8 = c & 3;
            const bf16* ga = Ab + (size_t)(bm + row) * stA + koff + k8 * 8;
            const bf16* gb = BT + (size_t)(bn + row) * ldb + k0 + k8 * 8;
            __builtin_amdgcn_global_load_lds((const GLOBAL_AS void*)ga,
                (LDS_AS void*)&lA[(wave * 128 + q * 64) * 8], 16, 0, 0);
            __builtin_amdgcn_global_load_lds((const GLOBAL_AS void*)gb,
                (LDS_AS void*)&lB[(wave * 128 + q * 64) * 8], 16, 0, 0);
        }
        __syncthreads();
        bf16x8 af[4], bfr[4];
#pragma unroll
        for (int mi = 0; mi < 4; ++mi)
            af[mi] = *reinterpret_cast<const bf16x8*>(&lA[(wr * 64 + mi * 16 + l15) * 32 + lg * 8]);
#pragma unroll
        for (int ni = 0; ni < 4; ++ni)
            bfr[ni] = *reinterpret_cast<const bf16x8*>(&lB[(wc * 64 + ni * 16 + l15) * 32 + lg * 8]);
#pragma unroll
        for (int mi = 0; mi < 4; ++mi)
#pragma unroll
            for (int ni = 0; ni < 4; ++ni)
                acc[mi][ni] = __builtin_amdgcn_mfma_f32_16x16x32_bf16(af[mi], bfr[ni], acc[mi][ni], 0, 0, 0);
        __syncthreads();
    }

#pragma unroll
    for (int mi = 0; mi < 4; ++mi)
#pragma unroll
        for (int ni = 0; ni < 4; ++ni) {
            const int r0 = bm + wr * 64 + mi * 16 + lg * 4;
            const int c0 = bn + wc * 64 + ni * 16 + l15;
#pragma unroll
            for (int i = 0; i < 4; ++i) {
                size_t idx = (size_t)(r0 + i) * Nn + c0;
                float v = acc[mi][ni][i];
                if (ACCUM) v += OUT[idx];
                OUT[idx] = v;
            }
        }
}

// ---------------------------------------------------------------------------
// Fused bias + LayerNorm + GELU; wave per row. grid N/4, block 256.
__global__ __launch_bounds__(256)
void ln_gelu_k(const float* __restrict__ ACC, const float* __restrict__ bias,
               const float* __restrict__ g, const float* __restrict__ b,
               bf16* __restrict__ hout) {
    const int wave = threadIdx.x >> 6, lane = threadIdx.x & 63;
    const int n = blockIdx.x * 4 + wave;
    float x[12];
    float s = 0.f, ss = 0.f;
#pragma unroll
    for (int j = 0; j < 12; ++j) {
        int c = lane + j * 64;
        x[j] = ACC[(size_t)n * DIM + c] + bias[c];
        s += x[j]; ss += x[j] * x[j];
    }
#pragma unroll
    for (int m = 1; m < 64; m <<= 1) { s += __shfl_xor(s, m, 64); ss += __shfl_xor(ss, m, 64); }
    const float mean = s * (1.f / DIM);
    const float var = ss * (1.f / DIM) - mean * mean;
    const float rstd = rsqrtf(var + 1e-5f);
#pragma unroll
    for (int j = 0; j < 12; ++j) {
        int c = lane + j * 64;
        float y = (x[j] - mean) * rstd * g[c] + b[c];
        hout[(size_t)n * DIM + c] = __float2bfloat16(gelu_f(y));
    }
}

// ---------------------------------------------------------------------------
__global__ __launch_bounds__(256)
void gate_k(const float* __restrict__ G1, const float* __restrict__ bg1,
            const float* __restrict__ Wg2, const float* __restrict__ bg2,
            float* __restrict__ gate) {
    const int wave = threadIdx.x >> 6, lane = threadIdx.x & 63;
    const int n = blockIdx.x * 4 + wave;
    float acc = 0.f;
#pragma unroll
    for (int j = 0; j < 6; ++j) {
        int c = lane + j * 64;
        float xv = G1[(size_t)n * 384 + c] + bg1[c];
        acc += gelu_f(xv) * Wg2[c];
    }
#pragma unroll
    for (int m = 1; m < 64; m <<= 1) acc += __shfl_xor(acc, m, 64);
    if (lane == 0) gate[n] = acc + bg2[0];
}

// ---------------------------------------------------------------------------
__device__ __forceinline__ int lower_bound_ng(const int* ng, int key) {
    int lo = 0, hi = N_NODES;
    while (lo < hi) { int mid = (lo + hi) >> 1; if (ng[mid] < key) lo = mid + 1; else hi = mid; }
    return lo;
}

__global__ __launch_bounds__(256)
void seg_stats_k(const float* __restrict__ gate, const int* __restrict__ ng,
                 float* __restrict__ gmax, float* __restrict__ gden) {
    __shared__ float red[256];
    const int b = blockIdx.x, t = threadIdx.x;
    const int start = lower_bound_ng(ng, b), end = lower_bound_ng(ng, b + 1);
    float m = -1e30f;
    for (int n = start + t; n < end; n += 256) m = fmaxf(m, gate[n]);
    red[t] = m; __syncthreads();
    for (int s = 128; s > 0; s >>= 1) { if (t < s) red[t] = fmaxf(red[t], red[t + s]); __syncthreads(); }
    const float gm = red[0]; __syncthreads();
    float ssum = 0.f;
    for (int n = start + t; n < end; n += 256) ssum += expf(gate[n] - gm);
    red[t] = ssum; __syncthreads();
    for (int s = 128; s > 0; s >>= 1) { if (t < s) red[t] += red[t + s]; __syncthreads(); }
    if (t == 0) { gmax[b] = gm; gden[b] = fmaxf(red[0], 1e-30f); }
}

__global__ __launch_bounds__(768)
void pool_k(const bf16* __restrict__ h, const float* __restrict__ gate,
            const int* __restrict__ ng, const float* __restrict__ gmax,
            const float* __restrict__ gden, float* __restrict__ grep) {
    const int b = blockIdx.x, c = threadIdx.x;
    const int start = lower_bound_ng(ng, b), end = lower_bound_ng(ng, b + 1);
    const float gm = gmax[b], inv = 1.0f / gden[b];
    const unsigned short* hv = (const unsigned short*)h;
    float a0 = 0.f, a1 = 0.f;
    int n = start;
    for (; n + 1 < end; n += 2) {
        float w0 = expf(gate[n] - gm) * inv;
        float w1 = expf(gate[n + 1] - gm) * inv;
        a0 += w0 * bfu(hv[(size_t)n * DIM + c]);
        a1 += w1 * bfu(hv[(size_t)(n + 1) * DIM + c]);
    }
    if (n < end) a0 += expf(gate[n] - gm) * inv * bfu(hv[(size_t)n * DIM + c]);
    grep[(size_t)b * DIM + c] = a0 + a1;
}

// ---------------------------------------------------------------------------
__global__ __launch_bounds__(512)
void cls_k(const float* __restrict__ grep, const float* __restrict__ Wc1,
           const float* __restrict__ bc1, const float* __restrict__ lng,
           const float* __restrict__ lnb, const float* __restrict__ Wc2,
           const float* __restrict__ bc2, float* __restrict__ out) {
    __shared__ float gr[DIM];
    __shared__ float red[512];
    const int b = blockIdx.x, j = threadIdx.x;
    for (int c = j; c < DIM; c += 512) gr[c] = grep[(size_t)b * DIM + c];
    __syncthreads();
    float a = bc1[j];
#pragma unroll 4
    for (int k = 0; k < DIM; ++k) a = fmaf(gr[k], Wc1[(size_t)k * 512 + j], a);
    red[j] = a; __syncthreads();
    for (int s = 256; s > 0; s >>= 1) { if (j < s) red[j] += red[j + s]; __syncthreads(); }
    const float mean = red[0] * (1.f / 512.f);
    __syncthreads();
    red[j] = (a - mean) * (a - mean); __syncthreads();
    for (int s = 256; s > 0; s >>= 1) { if (j < s) red[j] += red[j + s]; __syncthreads(); }
    const float rstd = rsqrtf(red[0] * (1.f / 512.f) + 1e-5f);
    __syncthreads();
    const float z = gelu_f((a - mean) * rstd * lng[j] + lnb[j]);
    red[j] = z * Wc2[2 * j + 0]; __syncthreads();
    for (int s = 256; s > 0; s >>= 1) { if (j < s) red[j] += red[j + s]; __syncthreads(); }
    const float l0 = red[0] + bc2[0];
    __syncthreads();
    red[j] = z * Wc2[2 * j + 1]; __syncthreads();
    for (int s = 256; s > 0; s >>= 1) { if (j < s) red[j] += red[j + s]; __syncthreads(); }
    if (j == 0) {
        const float l1 = red[0] + bc2[1];
        const float mx = fmaxf(l0, l1);
        const float lse = mx + logf(expf(l0 - mx) + expf(l1 - mx));
        out[2 * b + 0] = l0 - lse;
        out[2 * b + 1] = l1 - lse;
    }
}

// ---------------------------------------------------------------------------
extern "C" void kernel_launch(void* const* d_in, const int* in_sizes, int n_in,
                              void* d_out, int out_size, void* d_ws, size_t ws_size,
                              hipStream_t stream) {
    const float* type_vec = (const float*)d_in[0];
    const float* code_vec = (const float*)d_in[1];
    const float* W_in     = (const float*)d_in[2];
    const float* b_in     = (const float*)d_in[3];
    const float* ln_in_g  = (const float*)d_in[4];
    const float* ln_in_b  = (const float*)d_in[5];
    const float* W_rel    = (const float*)d_in[6];
    const float* W_loop   = (const float*)d_in[7];
    const float* rgcn_bias= (const float*)d_in[8];
    const float* ln_g     = (const float*)d_in[9];
    const float* ln_b     = (const float*)d_in[10];
    const float* Wg1      = (const float*)d_in[11];
    const float* bg1      = (const float*)d_in[12];
    const float* Wg2      = (const float*)d_in[13];
    const float* bg2      = (const float*)d_in[14];
    const float* Wc1      = (const float*)d_in[15];
    const float* bc1      = (const float*)d_in[16];
    const float* ln_c_g   = (const float*)d_in[17];
    const float* ln_c_b   = (const float*)d_in[18];
    const float* Wc2      = (const float*)d_in[19];
    const float* bc2      = (const float*)d_in[20];
    const int* src        = (const int*)d_in[21];
    const int* dst        = (const int*)d_in[22];
    const int* etype      = (const int*)d_in[23];
    const int* node_graph = (const int*)d_in[24];

    char* ws = (char*)d_ws;

    // pick relation-chunk width nc by workspace size
    auto need = [](int nc) -> size_t {
        size_t base = 0;
        auto al = [&](size_t sz) { size_t r = base; base = (base + sz + 255) & ~(size_t)255; (void)r; };
        al((size_t)N_NODES * DIM * 2);        // H
        al((size_t)N_NODES * DIM * 4);        // ACC
        al((size_t)DIM * KIN * 2);            // WIN
        al((size_t)3 * DIM * KSTACK * 2);     // WST
        al((size_t)384 * DIM * 2);            // WG1
        size_t open = base;
        al((size_t)N_NODES * nc * DIM * 2);   // AGG
        al((size_t)(N_NODES + 1) * 4);        // RP
        al((size_t)N_NODES * 4);              // CUR
        al((size_t)N_NODES * 4);              // DEG
        al((size_t)N_EDGES * 4);              // EIX
        al((size_t)N_NODES * 4);              // GATE
        al(256); al(256);                     // GMAX, GDEN
        al((size_t)NGR * DIM * 4);            // GREP
        size_t xend = open + (size_t)N_NODES * KIN * 2;
        return base > xend ? base : xend;
    };
    int nc = 1;
    if (ws_size >= need(4)) nc = 4;
    else if (ws_size >= need(2)) nc = 2;

    // layout
    size_t off = 0;
    auto alloc = [&](size_t sz) { size_t r = off; off = (off + sz + 255) & ~(size_t)255; return r; };
    bf16*  h_bf  = (bf16*)(ws + alloc((size_t)N_NODES * DIM * 2));
    float* ACC   = (float*)(ws + alloc((size_t)N_NODES * DIM * 4));
    bf16*  WinT  = (bf16*)(ws + alloc((size_t)DIM * KIN * 2));
    bf16*  Wst   = (bf16*)(ws + alloc((size_t)3 * DIM * KSTACK * 2));
    bf16*  Wg1T  = (bf16*)(ws + alloc((size_t)384 * DIM * 2));
    size_t open  = off;
    bf16*  AGG   = (bf16*)(ws + alloc((size_t)N_NODES * nc * DIM * 2));
    int*   row_ptr = (int*)(ws + alloc((size_t)(N_NODES + 1) * 4));
    int*   cursor  = (int*)(ws + alloc((size_t)N_NODES * 4));
    int*   deg     = (int*)(ws + alloc((size_t)N_NODES * 4));
    int*   eidx    = (int*)(ws + alloc((size_t)N_EDGES * 4));
    float* gate  = (float*)(ws + alloc((size_t)N_NODES * 4));
    float* gmax  = (float*)(ws + alloc(256));
    float* gden  = (float*)(ws + alloc(256));
    float* grep  = (float*)(ws + alloc((size_t)NGR * DIM * 4));
    bf16*  Xbf   = (bf16*)(ws + open);      // [N][800]; dead after input GEMM
    float* G1    = ACC;                     // reuse after layers

    // --- weight prep
    tcast_k<<<dim3(25, 24), 256, 0, stream>>>(W_in, WinT, 784, DIM, KIN, KIN);
    wprep_k<<<dim3(24, 24, 27), 256, 0, stream>>>(W_rel, W_loop, Wst);
    tcast_k<<<dim3(24, 12), 256, 0, stream>>>(Wg1, Wg1T, DIM, 384, DIM, DIM);

    // --- input projection (X overlaps AGG/CSR region; consumed before they're written)
    concat_k<<<N_NODES, 256, 0, stream>>>(type_vec, code_vec, Xbf);
    gemm_bt<0><<<dim3(DIM / 128, N_NODES / 128), 256, 0, stream>>>(
        Xbf, KIN, KIN, Xbf, KIN, WinT, KIN, ACC, DIM, KIN);
    ln_gelu_k<<<N_NODES / 4, 256, 0, stream>>>(ACC, b_in, ln_in_g, ln_in_b, h_bf);

    // --- CSR build (after X is dead)
    hipMemsetAsync(deg, 0, (size_t)N_NODES * 4, stream);
    hist_k<<<N_EDGES / 256, 256, 0, stream>>>(dst, deg);
    scan_k<<<1, 1024, 0, stream>>>(deg, row_ptr, cursor);
    place_k<<<N_EDGES / 256, 256, 0, stream>>>(src, dst, etype, cursor, eidx);

    // --- RGCN layers: per chunk of nc relations, gather then accumulate-GEMM
    const int nchunks = 8 / nc;
    for (int l = 0; l < 3; ++l) {
        bf16* Wl = Wst + (size_t)l * DIM * KSTACK;
        for (int c = 0; c < nchunks; ++c) {
            const int rbase = c * nc;
            if (nc == 1)      gather_k<1><<<N_NODES / 4, 256, 0, stream>>>(h_bf, row_ptr, eidx, AGG, rbase);
            else if (nc == 2) gather_k<2><<<N_NODES / 4, 256, 0, stream>>>(h_bf, row_ptr, eidx, AGG, rbase);
            else              gather_k<4><<<N_NODES / 4, 256, 0, stream>>>(h_bf, row_ptr, eidx, AGG, rbase);
            if (c == 0) {
                // self-loop (cols [0,768)) + first chunk (cols [768, 768+nc*768))
                gemm_bt<0><<<dim3(DIM / 128, N_NODES / 128), 256, 0, stream>>>(
                    h_bf, DIM, DIM, AGG, nc * DIM, Wl, KSTACK, ACC, DIM, DIM + nc * DIM);
            } else {
                gemm_bt<1><<<dim3(DIM / 128, N_NODES / 128), 256, 0, stream>>>(
                    AGG, nc * DIM, nc * DIM, AGG, nc * DIM,
                    Wl + DIM + c * nc * DIM, KSTACK, ACC, DIM, nc * DIM);
            }
        }
        ln_gelu_k<<<N_NODES / 4, 256, 0, stream>>>(ACC, rgcn_bias + l * DIM, ln_g + l * DIM,
                                                   ln_b + l * DIM, h_bf);
    }

    // --- global attention pooling
    gemm_bt<0><<<dim3(384 / 128, N_NODES / 128), 256, 0, stream>>>(
        h_bf, DIM, DIM, h_bf, DIM, Wg1T, DIM, G1, 384, DIM);
    gate_k<<<N_NODES / 4, 256, 0, stream>>>(G1, bg1, Wg2, bg2, gate);
    seg_stats_k<<<NGR, 256, 0, stream>>>(gate, node_graph, gmax, gden);
    pool_k<<<NGR, 768, 0, stream>>>(h_bf, gate, node_graph, gmax, gden, grep);

    // --- classifier head
    cls_k<<<NGR, 512, 0, stream>>>(grep, Wc1, bc1, ln_c_g, ln_c_b, Wc2, bc2, (float*)d_out);
}